// Round 3
// baseline (4348.565 us; speedup 1.0000x reference)
//
#include <hip/hip_runtime.h>
#include <hip/hip_bf16.h>

#define HID 64

// ---------------- degree / dinv ----------------

__global__ __launch_bounds__(256) void deg_kernel(const int* __restrict__ dst,
                                                  float* __restrict__ deg, int E) {
    int i = blockIdx.x * 256 + threadIdx.x;
    if (i < E) unsafeAtomicAdd(&deg[dst[i]], 1.0f);
}

__global__ __launch_bounds__(256) void dinv_kernel(float* __restrict__ deg, int N) {
    int i = blockIdx.x * 256 + threadIdx.x;
    if (i < N) deg[i] = rsqrtf(deg[i] + 1.0f);  // +1 = self-loop; deg>=1 always
}

// ---------------- GEMM h = X@W, scaled by dinv[row]; also init accum = g ----------------
// block = 256 threads = 4 rows x 64 cols. W (64x64 = 16KB) staged in LDS.

__global__ __launch_bounds__(256) void gemm_scale_kernel(
    const float* __restrict__ X, const float* __restrict__ W,
    const float* __restrict__ dinv, float* __restrict__ g,
    float* __restrict__ accum, int N) {
    __shared__ float Ws[HID * HID];
    __shared__ float xs[4 * HID];
    int tid = threadIdx.x;
    for (int i = tid; i < HID * HID; i += 256) Ws[i] = W[i];
    int lr = tid >> 6, c = tid & 63;
    int row = blockIdx.x * 4 + lr;
    if (row < N) xs[lr * HID + c] = X[(size_t)row * HID + c];
    __syncthreads();
    if (row >= N) return;
    float acc = 0.f;
#pragma unroll
    for (int k = 0; k < HID; ++k) acc = fmaf(xs[lr * HID + k], Ws[k * HID + c], acc);
    float v = acc * dinv[row];
    size_t o = (size_t)row * HID + c;
    g[o] = v;
    accum[o] = v;  // self-loop term: accum starts at g[n]
}

// ---------------- edge scatter: accum[dst] += g[src] ----------------
// one thread = one (edge, 4-feature quad): float4 gather + 4 native f32 atomics.

__global__ __launch_bounds__(256) void scatter_kernel(
    const int* __restrict__ src, const int* __restrict__ dst,
    const float* __restrict__ g, float* __restrict__ accum, int E) {
    long long idx = (long long)blockIdx.x * 256 + threadIdx.x;
    int e = (int)(idx >> 4);
    if (e >= E) return;
    int q = (int)(idx & 15);
    int s = src[e], d = dst[e];
    const float4 v = *reinterpret_cast<const float4*>(&g[(size_t)s * HID + q * 4]);
    float* out = &accum[(size_t)d * HID + q * 4];
    unsafeAtomicAdd(out + 0, v.x);
    unsafeAtomicAdd(out + 1, v.y);
    unsafeAtomicAdd(out + 2, v.z);
    unsafeAtomicAdd(out + 3, v.w);
}

// ---------------- finalize: out = dinv[n]*accum + b  (+relu) ----------------

template <bool RELU>
__global__ __launch_bounds__(256) void finalize_kernel(
    const float* __restrict__ accum, const float* __restrict__ dinv,
    const float* __restrict__ b, float* __restrict__ out, long long total) {
    long long i = (long long)blockIdx.x * 256 + threadIdx.x;
    if (i >= total) return;
    float v = dinv[i >> 6] * accum[i] + b[i & 63];
    if (RELU) v = fmaxf(v, 0.f);
    out[i] = v;
}

// ---------------- finalize + log_softmax over 64 features (wave per row) ----------------

__global__ __launch_bounds__(256) void finalize_lsm_kernel(
    const float* __restrict__ accum, const float* __restrict__ dinv,
    const float* __restrict__ b, float* __restrict__ out, int N) {
    int tid = threadIdx.x;
    int row = blockIdx.x * 4 + (tid >> 6);
    if (row >= N) return;
    int f = tid & 63;
    float v = dinv[row] * accum[(size_t)row * HID + f] + b[f];
    float m = v;
#pragma unroll
    for (int o = 32; o > 0; o >>= 1) m = fmaxf(m, __shfl_xor(m, o, 64));
    float ex = expf(v - m);
    float s = ex;
#pragma unroll
    for (int o = 32; o > 0; o >>= 1) s += __shfl_xor(s, o, 64);
    out[(size_t)row * HID + f] = v - m - logf(s);
}

extern "C" void kernel_launch(void* const* d_in, const int* in_sizes, int n_in,
                              void* d_out, int out_size, void* d_ws, size_t ws_size,
                              hipStream_t stream) {
    const float* x  = (const float*)d_in[0];
    const int*   ei = (const int*)d_in[1];
    const float* W1 = (const float*)d_in[2];
    const float* b1 = (const float*)d_in[3];
    const float* W2 = (const float*)d_in[4];
    const float* b2 = (const float*)d_in[5];

    const int N = in_sizes[0] / HID;   // 100000
    const int E = in_sizes[1] / 2;     // 1600000
    const int* src = ei;
    const int* dst = ei + E;

    float* ws    = (float*)d_ws;
    float* dinv  = ws;                                  // N floats
    size_t o1    = (((size_t)N) + 63) & ~(size_t)63;
    float* g     = ws + o1;                             // N*64
    float* accum = g + (size_t)N * HID;                 // N*64
    float* xbuf  = (float*)d_out;                       // intermediate activations

    const long long total = (long long)N * HID;
    const int gemm_grid   = (N + 3) / 4;
    const int ew_grid     = (int)((total + 255) / 256);
    const int scat_grid   = (int)(((long long)E * 16 + 255) / 256);

    // degrees (shared across all three convs)
    hipMemsetAsync(dinv, 0, (size_t)N * sizeof(float), stream);
    deg_kernel<<<(E + 255) / 256, 256, 0, stream>>>(dst, dinv, E);
    dinv_kernel<<<(N + 255) / 256, 256, 0, stream>>>(dinv, N);

    // conv1: W1, b1, no activation
    gemm_scale_kernel<<<gemm_grid, 256, 0, stream>>>(x, W1, dinv, g, accum, N);
    scatter_kernel<<<scat_grid, 256, 0, stream>>>(src, dst, g, accum, E);
    finalize_kernel<false><<<ew_grid, 256, 0, stream>>>(accum, dinv, b1, xbuf, total);

    // conv2: W1, b1, relu
    gemm_scale_kernel<<<gemm_grid, 256, 0, stream>>>(xbuf, W1, dinv, g, accum, N);
    scatter_kernel<<<scat_grid, 256, 0, stream>>>(src, dst, g, accum, E);
    finalize_kernel<true><<<ew_grid, 256, 0, stream>>>(accum, dinv, b1, xbuf, total);

    // conv3: W2, b2, log_softmax
    gemm_scale_kernel<<<gemm_grid, 256, 0, stream>>>(xbuf, W2, dinv, g, accum, N);
    scatter_kernel<<<scat_grid, 256, 0, stream>>>(src, dst, g, accum, E);
    finalize_lsm_kernel<<<gemm_grid, 256, 0, stream>>>(accum, dinv, b2, (float*)d_out, N);
}

// Round 4
// 680.394 us; speedup vs baseline: 6.3912x; 6.3912x over previous
//
#include <hip/hip_runtime.h>
#include <hip/hip_bf16.h>

#define HID 64

// ================= CSR build (by dst) =================

__global__ __launch_bounds__(256) void hist_kernel(const int* __restrict__ dst,
                                                   int* __restrict__ cnt, int E) {
    int i = blockIdx.x * 256 + threadIdx.x;
    if (i < E) atomicAdd(&cnt[dst[i]], 1);
}

// per-block (256-elem) sums of cnt
__global__ __launch_bounds__(256) void bsum_kernel(const int* __restrict__ cnt,
                                                   int* __restrict__ bsums, int N) {
    __shared__ int s[256];
    int tid = threadIdx.x, i = blockIdx.x * 256 + tid;
    s[tid] = (i < N) ? cnt[i] : 0;
    __syncthreads();
    for (int o = 128; o > 0; o >>= 1) {
        if (tid < o) s[tid] += s[tid + o];
        __syncthreads();
    }
    if (tid == 0) bsums[blockIdx.x] = s[0];
}

// exclusive scan of bsums in-place; nblk <= 512 (N=100k -> 391 blocks)
__global__ __launch_bounds__(512) void scan_bsums_kernel(int* __restrict__ bsums, int nblk) {
    __shared__ int s[512];
    int tid = threadIdx.x;
    int orig = (tid < nblk) ? bsums[tid] : 0;
    s[tid] = orig;
    __syncthreads();
    for (int off = 1; off < 512; off <<= 1) {
        int v = (tid >= off) ? s[tid - off] : 0;
        __syncthreads();
        s[tid] += v;
        __syncthreads();
    }
    if (tid < nblk) bsums[tid] = s[tid] - orig;
}

// row_ptr = blockBase + intra-block exclusive scan; also cursor copy + dinv
__global__ __launch_bounds__(256) void rowptr_kernel(
    const int* __restrict__ cnt, const int* __restrict__ bsums,
    int* __restrict__ row_ptr, int* __restrict__ cursor,
    float* __restrict__ dinv, int N) {
    __shared__ int s[256];
    int tid = threadIdx.x, i = blockIdx.x * 256 + tid;
    int c = (i < N) ? cnt[i] : 0;
    s[tid] = c;
    __syncthreads();
    for (int off = 1; off < 256; off <<= 1) {
        int v = (tid >= off) ? s[tid - off] : 0;
        __syncthreads();
        s[tid] += v;
        __syncthreads();
    }
    if (i < N) {
        int excl = s[tid] - c + bsums[blockIdx.x];
        row_ptr[i] = excl;
        cursor[i]  = excl;
        dinv[i]    = rsqrtf((float)c + 1.0f);  // +1 = self-loop
    }
}

__global__ __launch_bounds__(256) void fill_kernel(const int* __restrict__ src,
                                                   const int* __restrict__ dst,
                                                   int* __restrict__ cursor,
                                                   int* __restrict__ col, int E) {
    int i = blockIdx.x * 256 + threadIdx.x;
    if (i < E) {
        int p = atomicAdd(&cursor[dst[i]], 1);
        col[p] = src[i];
    }
}

// ================= GEMM: g = (X@W) * dinv[row] =================
// block = 256 = 4 rows x 64 cols; W staged in LDS.

__global__ __launch_bounds__(256) void gemm_scale_kernel(
    const float* __restrict__ X, const float* __restrict__ W,
    const float* __restrict__ dinv, float* __restrict__ g, int N) {
    __shared__ float Ws[HID * HID];
    __shared__ float xs[4 * HID];
    int tid = threadIdx.x;
    for (int i = tid; i < HID * HID; i += 256) Ws[i] = W[i];
    int lr = tid >> 6, c = tid & 63;
    int row = blockIdx.x * 4 + lr;
    if (row < N) xs[lr * HID + c] = X[(size_t)row * HID + c];
    __syncthreads();
    if (row >= N) return;
    float acc = 0.f;
#pragma unroll
    for (int k = 0; k < HID; ++k) acc = fmaf(xs[lr * HID + k], Ws[k * HID + c], acc);
    g[(size_t)row * HID + c] = acc * dinv[row];
}

// ================= gather-reduce + fused finalize =================
// one wave per node; lane = feature. out[n] = dinv[n]*(g[n] + sum g[col]) + b
// EPI: 0 = none, 1 = relu, 2 = log_softmax

template <int EPI>
__global__ __launch_bounds__(256) void aggregate_kernel(
    const float* __restrict__ g, const int* __restrict__ row_ptr,
    const int* __restrict__ cnt, const int* __restrict__ col,
    const float* __restrict__ dinv, const float* __restrict__ b,
    float* __restrict__ out, int N) {
    int tid = threadIdx.x;
    int n = blockIdx.x * 4 + (tid >> 6);
    if (n >= N) return;
    int lane = tid & 63;
    int beg = row_ptr[n], deg = cnt[n];
    float acc = g[(size_t)n * HID + lane];  // self-loop term
    for (int base = 0; base < deg; base += 64) {
        int rem = deg - base;
        int m = rem < 64 ? rem : 64;
        int c = (lane < rem) ? col[beg + base + lane] : 0;  // coalesced edge-list read
        for (int j = 0; j < m; ++j) {
            int s = __shfl(c, j, 64);                        // broadcast edge src
            acc += g[(size_t)s * HID + lane];                // 256B coalesced row read
        }
    }
    float v = dinv[n] * acc + b[lane];
    if (EPI == 1) v = fmaxf(v, 0.f);
    if (EPI == 2) {
        float mx = v;
#pragma unroll
        for (int o = 32; o > 0; o >>= 1) mx = fmaxf(mx, __shfl_xor(mx, o, 64));
        float ex = expf(v - mx);
        float sum = ex;
#pragma unroll
        for (int o = 32; o > 0; o >>= 1) sum += __shfl_xor(sum, o, 64);
        v = v - mx - logf(sum);
    }
    out[(size_t)n * HID + lane] = v;
}

// ================= launcher =================

static inline size_t alignup(size_t x) { return (x + 255) & ~(size_t)255; }

extern "C" void kernel_launch(void* const* d_in, const int* in_sizes, int n_in,
                              void* d_out, int out_size, void* d_ws, size_t ws_size,
                              hipStream_t stream) {
    const float* x  = (const float*)d_in[0];
    const int*   ei = (const int*)d_in[1];
    const float* W1 = (const float*)d_in[2];
    const float* b1 = (const float*)d_in[3];
    const float* W2 = (const float*)d_in[4];
    const float* b2 = (const float*)d_in[5];

    const int N = in_sizes[0] / HID;  // 100000
    const int E = in_sizes[1] / 2;    // 1600000
    const int* src = ei;
    const int* dst = ei + E;

    const int nblk = (N + 255) / 256;  // 391 (<=512 required by scan)

    char* w = (char*)d_ws;
    float* dinv    = (float*)w; w += alignup((size_t)N * 4);
    float* g       = (float*)w; w += alignup((size_t)N * HID * 4);
    int*   cnt     = (int*)w;   w += alignup((size_t)N * 4);
    int*   row_ptr = (int*)w;   w += alignup((size_t)N * 4);
    int*   cursor  = (int*)w;   w += alignup((size_t)N * 4);
    int*   col     = (int*)w;   w += alignup((size_t)E * 4);
    int*   bsums   = (int*)w;   w += alignup((size_t)nblk * 4);

    float* xbuf = (float*)d_out;  // intermediate activations live in d_out

    const int egrid = (E + 255) / 256;
    const int ngrid = (N + 3) / 4;  // gemm + aggregate grids

    // ---- CSR build (once; reused by all 3 convs) ----
    hipMemsetAsync(cnt, 0, (size_t)N * sizeof(int), stream);
    hist_kernel<<<egrid, 256, 0, stream>>>(dst, cnt, E);
    bsum_kernel<<<nblk, 256, 0, stream>>>(cnt, bsums, N);
    scan_bsums_kernel<<<1, 512, 0, stream>>>(bsums, nblk);
    rowptr_kernel<<<nblk, 256, 0, stream>>>(cnt, bsums, row_ptr, cursor, dinv, N);
    fill_kernel<<<egrid, 256, 0, stream>>>(src, dst, cursor, col, E);

    // ---- conv1: W1,b1 ----
    gemm_scale_kernel<<<ngrid, 256, 0, stream>>>(x, W1, dinv, g, N);
    aggregate_kernel<0><<<ngrid, 256, 0, stream>>>(g, row_ptr, cnt, col, dinv, b1, xbuf, N);

    // ---- conv2: W1,b1 + relu ----
    gemm_scale_kernel<<<ngrid, 256, 0, stream>>>(xbuf, W1, dinv, g, N);
    aggregate_kernel<1><<<ngrid, 256, 0, stream>>>(g, row_ptr, cnt, col, dinv, b1, xbuf, N);

    // ---- conv3: W2,b2 + log_softmax ----
    gemm_scale_kernel<<<ngrid, 256, 0, stream>>>(xbuf, W2, dinv, g, N);
    aggregate_kernel<2><<<ngrid, 256, 0, stream>>>(g, row_ptr, cnt, col, dinv, b2, (float*)d_out, N);
}

// Round 6
// 602.933 us; speedup vs baseline: 7.2124x; 1.1285x over previous
//
#include <hip/hip_runtime.h>
#include <hip/hip_bf16.h>

#define HID 64

// ================= CSR build (by dst) =================

__global__ __launch_bounds__(256) void hist_kernel(const int* __restrict__ dst,
                                                   int* __restrict__ cnt, int E) {
    int i = blockIdx.x * 256 + threadIdx.x;
    if (i < E) atomicAdd(&cnt[dst[i]], 1);
}

// per-block (256-elem) sums of cnt
__global__ __launch_bounds__(256) void bsum_kernel(const int* __restrict__ cnt,
                                                   int* __restrict__ bsums, int N) {
    __shared__ int s[256];
    int tid = threadIdx.x, i = blockIdx.x * 256 + tid;
    s[tid] = (i < N) ? cnt[i] : 0;
    __syncthreads();
    for (int o = 128; o > 0; o >>= 1) {
        if (tid < o) s[tid] += s[tid + o];
        __syncthreads();
    }
    if (tid == 0) bsums[blockIdx.x] = s[0];
}

// exclusive scan of bsums in-place; nblk <= 512 (N=100k -> 391 blocks)
__global__ __launch_bounds__(512) void scan_bsums_kernel(int* __restrict__ bsums, int nblk) {
    __shared__ int s[512];
    int tid = threadIdx.x;
    int orig = (tid < nblk) ? bsums[tid] : 0;
    s[tid] = orig;
    __syncthreads();
    for (int off = 1; off < 512; off <<= 1) {
        int v = (tid >= off) ? s[tid - off] : 0;
        __syncthreads();
        s[tid] += v;
        __syncthreads();
    }
    if (tid < nblk) bsums[tid] = s[tid] - orig;
}

// row_ptr = blockBase + intra-block exclusive scan; also cursor copy + dinv
__global__ __launch_bounds__(256) void rowptr_kernel(
    const int* __restrict__ cnt, const int* __restrict__ bsums,
    int* __restrict__ row_ptr, int* __restrict__ cursor,
    float* __restrict__ dinv, int N) {
    __shared__ int s[256];
    int tid = threadIdx.x, i = blockIdx.x * 256 + tid;
    int c = (i < N) ? cnt[i] : 0;
    s[tid] = c;
    __syncthreads();
    for (int off = 1; off < 256; off <<= 1) {
        int v = (tid >= off) ? s[tid - off] : 0;
        __syncthreads();
        s[tid] += v;
        __syncthreads();
    }
    if (i < N) {
        int excl = s[tid] - c + bsums[blockIdx.x];
        row_ptr[i] = excl;
        cursor[i]  = excl;
        dinv[i]    = rsqrtf((float)c + 1.0f);  // +1 = self-loop
    }
}

// partitioned fill: 8 replicas per edge-chunk; replica p fills only dst range p.
// blockIdx%8 tracks XCD round-robin -> each XCD's col writes stay in a ~0.8MB
// L2-resident window (lines go fully dirty before writeback). Correct even if
// the XCD mapping assumption is wrong (each edge matched by exactly one replica).
__global__ __launch_bounds__(256) void fill_part_kernel(
    const int* __restrict__ src, const int* __restrict__ dst,
    int* __restrict__ cursor, int* __restrict__ col, int E, int psz) {
    int part  = blockIdx.x & 7;
    int chunk = blockIdx.x >> 3;
    int i = chunk * 256 + threadIdx.x;
    if (i >= E) return;
    int d = dst[i];
    if (d / psz == part) {
        int p = atomicAdd(&cursor[d], 1);
        col[p] = src[i];
    }
}

// ================= GEMM: g = (X@W) * dinv[row] =================
// block = 256 = 4 rows x 64 cols; W staged in LDS.

__global__ __launch_bounds__(256) void gemm_scale_kernel(
    const float* __restrict__ X, const float* __restrict__ W,
    const float* __restrict__ dinv, float* __restrict__ g, int N) {
    __shared__ float Ws[HID * HID];
    __shared__ float xs[4 * HID];
    int tid = threadIdx.x;
    for (int i = tid; i < HID * HID; i += 256) Ws[i] = W[i];
    int lr = tid >> 6, c = tid & 63;
    int row = blockIdx.x * 4 + lr;
    if (row < N) xs[lr * HID + c] = X[(size_t)row * HID + c];
    __syncthreads();
    if (row >= N) return;
    float acc = 0.f;
#pragma unroll
    for (int k = 0; k < HID; ++k) acc = fmaf(xs[lr * HID + k], Ws[k * HID + c], acc);
    g[(size_t)row * HID + c] = acc * dinv[row];
}

// ================= gather-reduce + fused finalize =================
// one wave per node; lane = feature. 4 independent accumulators break the
// load-latency dependence chain (4-deep memory-level parallelism).
// EPI: 0 = none, 1 = relu, 2 = log_softmax

template <int EPI>
__global__ __launch_bounds__(256) void aggregate_kernel(
    const float* __restrict__ g, const int* __restrict__ row_ptr,
    const int* __restrict__ cnt, const int* __restrict__ col,
    const float* __restrict__ dinv, const float* __restrict__ b,
    float* __restrict__ out, int N) {
    int tid = threadIdx.x;
    int n = blockIdx.x * 4 + (tid >> 6);
    if (n >= N) return;
    int lane = tid & 63;
    int beg = row_ptr[n], deg = cnt[n];
    float a0 = g[(size_t)n * HID + lane];  // self-loop term
    float a1 = 0.f, a2 = 0.f, a3 = 0.f;

    int base = 0;
    for (; base + 64 <= deg; base += 64) {      // full 64-edge batches (rare)
        int c = col[beg + base + lane];
#pragma unroll
        for (int j = 0; j < 64; j += 4) {
            int s0 = __shfl(c, j, 64), s1 = __shfl(c, j + 1, 64);
            int s2 = __shfl(c, j + 2, 64), s3 = __shfl(c, j + 3, 64);
            a0 += g[(size_t)s0 * HID + lane];
            a1 += g[(size_t)s1 * HID + lane];
            a2 += g[(size_t)s2 * HID + lane];
            a3 += g[(size_t)s3 * HID + lane];
        }
    }
    int rem = deg - base;
    if (rem > 0) {
        int c = (lane < rem) ? col[beg + base + lane] : 0;
        int j = 0;
        for (; j + 4 <= rem; j += 4) {
            int s0 = __shfl(c, j, 64), s1 = __shfl(c, j + 1, 64);
            int s2 = __shfl(c, j + 2, 64), s3 = __shfl(c, j + 3, 64);
            a0 += g[(size_t)s0 * HID + lane];
            a1 += g[(size_t)s1 * HID + lane];
            a2 += g[(size_t)s2 * HID + lane];
            a3 += g[(size_t)s3 * HID + lane];
        }
        for (; j < rem; ++j) {
            int s0 = __shfl(c, j, 64);
            a0 += g[(size_t)s0 * HID + lane];
        }
    }

    float v = dinv[n] * ((a0 + a1) + (a2 + a3)) + b[lane];
    if (EPI == 1) v = fmaxf(v, 0.f);
    if (EPI == 2) {
        float mx = v;
#pragma unroll
        for (int o = 32; o > 0; o >>= 1) mx = fmaxf(mx, __shfl_xor(mx, o, 64));
        float ex = expf(v - mx);
        float sum = ex;
#pragma unroll
        for (int o = 32; o > 0; o >>= 1) sum += __shfl_xor(sum, o, 64);
        v = v - mx - logf(sum);
    }
    out[(size_t)n * HID + lane] = v;
}

// ================= launcher =================

static inline size_t alignup(size_t x) { return (x + 255) & ~(size_t)255; }

extern "C" void kernel_launch(void* const* d_in, const int* in_sizes, int n_in,
                              void* d_out, int out_size, void* d_ws, size_t ws_size,
                              hipStream_t stream) {
    const float* x  = (const float*)d_in[0];
    const int*   ei = (const int*)d_in[1];
    const float* W1 = (const float*)d_in[2];
    const float* b1 = (const float*)d_in[3];
    const float* W2 = (const float*)d_in[4];
    const float* b2 = (const float*)d_in[5];

    const int N = in_sizes[0] / HID;  // 100000
    const int E = in_sizes[1] / 2;    // 1600000
    const int* src = ei;
    const int* dst = ei + E;

    const int nblk = (N + 255) / 256;  // 391 (<=512 required by scan)
    const int psz  = (N + 7) / 8;      // dst-range partition size

    char* w = (char*)d_ws;
    float* dinv    = (float*)w; w += alignup((size_t)N * 4);
    float* g       = (float*)w; w += alignup((size_t)N * HID * 4);
    int*   cnt     = (int*)w;   w += alignup((size_t)N * 4);
    int*   row_ptr = (int*)w;   w += alignup((size_t)N * 4);
    int*   cursor  = (int*)w;   w += alignup((size_t)N * 4);
    int*   col     = (int*)w;   w += alignup((size_t)E * 4);
    int*   bsums   = (int*)w;   w += alignup((size_t)nblk * 4);

    float* xbuf = (float*)d_out;  // intermediate activations live in d_out

    const int egrid = (E + 255) / 256;
    const int ngrid = (N + 3) / 4;  // gemm + aggregate grids

    // ---- CSR build (once; reused by all 3 convs) ----
    hipMemsetAsync(cnt, 0, (size_t)N * sizeof(int), stream);
    hist_kernel<<<egrid, 256, 0, stream>>>(dst, cnt, E);
    bsum_kernel<<<nblk, 256, 0, stream>>>(cnt, bsums, N);
    scan_bsums_kernel<<<1, 512, 0, stream>>>(bsums, nblk);
    rowptr_kernel<<<nblk, 256, 0, stream>>>(cnt, bsums, row_ptr, cursor, dinv, N);
    fill_part_kernel<<<egrid * 8, 256, 0, stream>>>(src, dst, cursor, col, E, psz);

    // ---- conv1: W1,b1 ----
    gemm_scale_kernel<<<ngrid, 256, 0, stream>>>(x, W1, dinv, g, N);
    aggregate_kernel<0><<<ngrid, 256, 0, stream>>>(g, row_ptr, cnt, col, dinv, b1, xbuf, N);

    // ---- conv2: W1,b1 + relu ----
    gemm_scale_kernel<<<ngrid, 256, 0, stream>>>(xbuf, W1, dinv, g, N);
    aggregate_kernel<1><<<ngrid, 256, 0, stream>>>(g, row_ptr, cnt, col, dinv, b1, xbuf, N);

    // ---- conv3: W2,b2 + log_softmax ----
    gemm_scale_kernel<<<ngrid, 256, 0, stream>>>(xbuf, W2, dinv, g, N);
    aggregate_kernel<2><<<ngrid, 256, 0, stream>>>(g, row_ptr, cnt, col, dinv, b2, (float*)d_out, N);
}

// Round 7
// 480.944 us; speedup vs baseline: 9.0417x; 1.2536x over previous
//
#include <hip/hip_runtime.h>
#include <hip/hip_bf16.h>

#define HID 64

// ================= CSR build (by dst) =================

__global__ __launch_bounds__(256) void hist_kernel(const int* __restrict__ dst,
                                                   int* __restrict__ cnt, int E) {
    int i = blockIdx.x * 256 + threadIdx.x;
    if (i < E) atomicAdd(&cnt[dst[i]], 1);
}

// per-block (256-elem) sums of cnt
__global__ __launch_bounds__(256) void bsum_kernel(const int* __restrict__ cnt,
                                                   int* __restrict__ bsums, int N) {
    __shared__ int s[256];
    int tid = threadIdx.x, i = blockIdx.x * 256 + tid;
    s[tid] = (i < N) ? cnt[i] : 0;
    __syncthreads();
    for (int o = 128; o > 0; o >>= 1) {
        if (tid < o) s[tid] += s[tid + o];
        __syncthreads();
    }
    if (tid == 0) bsums[blockIdx.x] = s[0];
}

// exclusive scan of bsums in-place; nblk <= 512 (N=100k -> 391 blocks)
__global__ __launch_bounds__(512) void scan_bsums_kernel(int* __restrict__ bsums, int nblk) {
    __shared__ int s[512];
    int tid = threadIdx.x;
    int orig = (tid < nblk) ? bsums[tid] : 0;
    s[tid] = orig;
    __syncthreads();
    for (int off = 1; off < 512; off <<= 1) {
        int v = (tid >= off) ? s[tid - off] : 0;
        __syncthreads();
        s[tid] += v;
        __syncthreads();
    }
    if (tid < nblk) bsums[tid] = s[tid] - orig;
}

// row_ptr = blockBase + intra-block exclusive scan; also cursor copy + dinv
__global__ __launch_bounds__(256) void rowptr_kernel(
    const int* __restrict__ cnt, const int* __restrict__ bsums,
    int* __restrict__ row_ptr, int* __restrict__ cursor,
    float* __restrict__ dinv, int N) {
    __shared__ int s[256];
    int tid = threadIdx.x, i = blockIdx.x * 256 + tid;
    int c = (i < N) ? cnt[i] : 0;
    s[tid] = c;
    __syncthreads();
    for (int off = 1; off < 256; off <<= 1) {
        int v = (tid >= off) ? s[tid - off] : 0;
        __syncthreads();
        s[tid] += v;
        __syncthreads();
    }
    if (i < N) {
        int excl = s[tid] - c + bsums[blockIdx.x];
        row_ptr[i] = excl;
        cursor[i]  = excl;
        dinv[i]    = rsqrtf((float)c + 1.0f);  // +1 = self-loop
    }
}

// partitioned fill: 8 replicas per edge-chunk; replica p fills only dst range p.
// Keeps each XCD's col writes in a ~0.8MB L2-resident window.
__global__ __launch_bounds__(256) void fill_part_kernel(
    const int* __restrict__ src, const int* __restrict__ dst,
    int* __restrict__ cursor, int* __restrict__ col, int E, int psz) {
    int part  = blockIdx.x & 7;
    int chunk = blockIdx.x >> 3;
    int i = chunk * 256 + threadIdx.x;
    if (i >= E) return;
    int d = dst[i];
    if (d / psz == part) {
        int p = atomicAdd(&cursor[d], 1);
        col[p] = src[i];
    }
}

// ================= GEMM: g = (X@W) * dinv[row] =================
// block = 256 = 4 rows x 64 cols; W staged in LDS. Row N is the sentinel
// zero row used by the aggregate's padded gather.

__global__ __launch_bounds__(256) void gemm_scale_kernel(
    const float* __restrict__ X, const float* __restrict__ W,
    const float* __restrict__ dinv, float* __restrict__ g, int N) {
    __shared__ float Ws[HID * HID];
    __shared__ float xs[4 * HID];
    int tid = threadIdx.x;
    for (int i = tid; i < HID * HID; i += 256) Ws[i] = W[i];
    int lr = tid >> 6, c = tid & 63;
    int row = blockIdx.x * 4 + lr;
    if (row < N) xs[lr * HID + c] = X[(size_t)row * HID + c];
    __syncthreads();
    if (row >= N) {
        if (row == N) g[(size_t)row * HID + c] = 0.f;  // sentinel zero row
        return;
    }
    float acc = 0.f;
#pragma unroll
    for (int k = 0; k < HID; ++k) acc = fmaf(xs[lr * HID + k], Ws[k * HID + c], acc);
    g[(size_t)row * HID + c] = acc * dinv[row];
}

// ================= gather-reduce + fused finalize =================
// one wave per node. float2 lanes: fp = lane&31 covers features {2fp,2fp+1};
// half = lane>>5 selects even/odd edge of a pair -> one wave-load gathers TWO
// edge rows (2x bytes in flight per round vs scalar lanes). OOB pair slots
// resolve to sentinel row N (zeros) via the shfl of padded col values.
// EPI: 0 = none, 1 = relu, 2 = log_softmax

template <int EPI>
__global__ __launch_bounds__(256) void aggregate_kernel(
    const float* __restrict__ g, const int* __restrict__ row_ptr,
    const int* __restrict__ cnt, const int* __restrict__ col,
    const float* __restrict__ dinv, const float* __restrict__ b,
    float* __restrict__ out, int N) {
    int tid = threadIdx.x;
    int n = blockIdx.x * 4 + (tid >> 6);
    if (n >= N) return;
    int lane = tid & 63;
    int half = lane >> 5;   // which edge of the pair
    int fp   = lane & 31;   // feature-pair index

    int beg = __builtin_amdgcn_readfirstlane(row_ptr[n]);
    int deg = __builtin_amdgcn_readfirstlane(cnt[n]);
    float dn = __builtin_amdgcn_readfirstlane(__float_as_uint(dinv[n])) ?
               __uint_as_float(__builtin_amdgcn_readfirstlane(__float_as_uint(dinv[n]))) : 0.f;
    dn = __uint_as_float(__builtin_amdgcn_readfirstlane(__float_as_uint(dinv[n])));

    const float2* g2 = (const float2*)g;
    float2 self = g2[(size_t)n * 32 + fp];          // issued early
    float2 bb   = ((const float2*)b)[fp];

    float2 a0 = make_float2(0.f, 0.f), a1 = a0, a2 = a0, a3 = a0;

    int base = 0;
    for (; base + 64 <= deg; base += 64) {          // full batches (rare at deg~16)
        int c = col[beg + base + lane];
#pragma unroll
        for (int jj = 0; jj < 32; jj += 4) {
            int s0 = __shfl(c, 2 * (jj + 0) + half, 64);
            int s1 = __shfl(c, 2 * (jj + 1) + half, 64);
            int s2 = __shfl(c, 2 * (jj + 2) + half, 64);
            int s3 = __shfl(c, 2 * (jj + 3) + half, 64);
            float2 v0 = g2[(size_t)s0 * 32 + fp];
            float2 v1 = g2[(size_t)s1 * 32 + fp];
            float2 v2 = g2[(size_t)s2 * 32 + fp];
            float2 v3 = g2[(size_t)s3 * 32 + fp];
            a0.x += v0.x; a0.y += v0.y;
            a1.x += v1.x; a1.y += v1.y;
            a2.x += v2.x; a2.y += v2.y;
            a3.x += v3.x; a3.y += v3.y;
        }
    }
    int rem = deg - base;
    if (rem > 0) {
        int c = (lane < rem) ? col[beg + base + lane] : N;  // pad with sentinel
        int pairs = (rem + 1) >> 1;
        int jj = 0;
        for (; jj + 4 <= pairs; jj += 4) {
            int s0 = __shfl(c, 2 * (jj + 0) + half, 64);
            int s1 = __shfl(c, 2 * (jj + 1) + half, 64);
            int s2 = __shfl(c, 2 * (jj + 2) + half, 64);
            int s3 = __shfl(c, 2 * (jj + 3) + half, 64);
            float2 v0 = g2[(size_t)s0 * 32 + fp];
            float2 v1 = g2[(size_t)s1 * 32 + fp];
            float2 v2 = g2[(size_t)s2 * 32 + fp];
            float2 v3 = g2[(size_t)s3 * 32 + fp];
            a0.x += v0.x; a0.y += v0.y;
            a1.x += v1.x; a1.y += v1.y;
            a2.x += v2.x; a2.y += v2.y;
            a3.x += v3.x; a3.y += v3.y;
        }
        for (; jj < pairs; ++jj) {
            int s0 = __shfl(c, 2 * jj + half, 64);
            float2 v0 = g2[(size_t)s0 * 32 + fp];
            a0.x += v0.x; a0.y += v0.y;
        }
    }

    float2 t;
    t.x = (a0.x + a1.x) + (a2.x + a3.x);
    t.y = (a0.y + a1.y) + (a2.y + a3.y);
    // combine even/odd-edge halves (lanes l and l^32 hold the two partials)
    t.x += __shfl_xor(t.x, 32, 64);
    t.y += __shfl_xor(t.y, 32, 64);
    t.x += self.x;
    t.y += self.y;

    float vx = dn * t.x + bb.x;
    float vy = dn * t.y + bb.y;
    if (EPI == 1) { vx = fmaxf(vx, 0.f); vy = fmaxf(vy, 0.f); }
    if (EPI == 2) {
        float mx = fmaxf(vx, vy);
#pragma unroll
        for (int o = 16; o > 0; o >>= 1) mx = fmaxf(mx, __shfl_xor(mx, o, 64));
        float sum = expf(vx - mx) + expf(vy - mx);
#pragma unroll
        for (int o = 16; o > 0; o >>= 1) sum += __shfl_xor(sum, o, 64);
        float ls = logf(sum);
        vx = vx - mx - ls;
        vy = vy - mx - ls;
    }
    if (half == 0) ((float2*)out)[(size_t)n * 32 + fp] = make_float2(vx, vy);
}

// ================= launcher =================

static inline size_t alignup(size_t x) { return (x + 255) & ~(size_t)255; }

extern "C" void kernel_launch(void* const* d_in, const int* in_sizes, int n_in,
                              void* d_out, int out_size, void* d_ws, size_t ws_size,
                              hipStream_t stream) {
    const float* x  = (const float*)d_in[0];
    const int*   ei = (const int*)d_in[1];
    const float* W1 = (const float*)d_in[2];
    const float* b1 = (const float*)d_in[3];
    const float* W2 = (const float*)d_in[4];
    const float* b2 = (const float*)d_in[5];

    const int N = in_sizes[0] / HID;  // 100000
    const int E = in_sizes[1] / 2;    // 1600000
    const int* src = ei;
    const int* dst = ei + E;

    const int nblk = (N + 255) / 256;  // 391 (<=512 required by scan)
    const int psz  = (N + 7) / 8;      // dst-range partition size

    char* w = (char*)d_ws;
    float* dinv    = (float*)w; w += alignup((size_t)N * 4);
    float* g       = (float*)w; w += alignup((size_t)(N + 1) * HID * 4);  // +1 sentinel row
    int*   cnt     = (int*)w;   w += alignup((size_t)N * 4);
    int*   row_ptr = (int*)w;   w += alignup((size_t)N * 4);
    int*   cursor  = (int*)w;   w += alignup((size_t)N * 4);
    int*   col     = (int*)w;   w += alignup((size_t)E * 4);
    int*   bsums   = (int*)w;   w += alignup((size_t)nblk * 4);

    float* xbuf = (float*)d_out;  // intermediate activations live in d_out

    const int egrid = (E + 255) / 256;
    const int ngrid = (N + 3) / 4;       // aggregate grid
    const int ggrid = (N + 1 + 3) / 4;   // gemm grid covers sentinel row N

    // ---- CSR build (once; reused by all 3 convs) ----
    hipMemsetAsync(cnt, 0, (size_t)N * sizeof(int), stream);
    hist_kernel<<<egrid, 256, 0, stream>>>(dst, cnt, E);
    bsum_kernel<<<nblk, 256, 0, stream>>>(cnt, bsums, N);
    scan_bsums_kernel<<<1, 512, 0, stream>>>(bsums, nblk);
    rowptr_kernel<<<nblk, 256, 0, stream>>>(cnt, bsums, row_ptr, cursor, dinv, N);
    fill_part_kernel<<<egrid * 8, 256, 0, stream>>>(src, dst, cursor, col, E, psz);

    // ---- conv1: W1,b1 ----
    gemm_scale_kernel<<<ggrid, 256, 0, stream>>>(x, W1, dinv, g, N);
    aggregate_kernel<0><<<ngrid, 256, 0, stream>>>(g, row_ptr, cnt, col, dinv, b1, xbuf, N);

    // ---- conv2: W1,b1 + relu ----
    gemm_scale_kernel<<<ggrid, 256, 0, stream>>>(xbuf, W1, dinv, g, N);
    aggregate_kernel<1><<<ngrid, 256, 0, stream>>>(g, row_ptr, cnt, col, dinv, b1, xbuf, N);

    // ---- conv3: W2,b2 + log_softmax ----
    gemm_scale_kernel<<<ggrid, 256, 0, stream>>>(xbuf, W2, dinv, g, N);
    aggregate_kernel<2><<<ngrid, 256, 0, stream>>>(g, row_ptr, cnt, col, dinv, b2, (float*)d_out, N);
}

// Round 8
// 463.368 us; speedup vs baseline: 9.3847x; 1.0379x over previous
//
#include <hip/hip_runtime.h>
#include <hip/hip_bf16.h>

#define HID 64

__device__ __forceinline__ float bf2f(unsigned short u) {
    return __uint_as_float(((unsigned)u) << 16);
}

// ================= CSR build (by dst) =================

__global__ __launch_bounds__(256) void hist_kernel(const int* __restrict__ dst,
                                                   int* __restrict__ cnt, int E) {
    int i = blockIdx.x * 256 + threadIdx.x;
    if (i < E) atomicAdd(&cnt[dst[i]], 1);
}

// per-block (256-elem) sums of cnt
__global__ __launch_bounds__(256) void bsum_kernel(const int* __restrict__ cnt,
                                                   int* __restrict__ bsums, int N) {
    __shared__ int s[256];
    int tid = threadIdx.x, i = blockIdx.x * 256 + tid;
    s[tid] = (i < N) ? cnt[i] : 0;
    __syncthreads();
    for (int o = 128; o > 0; o >>= 1) {
        if (tid < o) s[tid] += s[tid + o];
        __syncthreads();
    }
    if (tid == 0) bsums[blockIdx.x] = s[0];
}

// exclusive scan of bsums in-place; nblk <= 512 (N=100k -> 391 blocks)
__global__ __launch_bounds__(512) void scan_bsums_kernel(int* __restrict__ bsums, int nblk) {
    __shared__ int s[512];
    int tid = threadIdx.x;
    int orig = (tid < nblk) ? bsums[tid] : 0;
    s[tid] = orig;
    __syncthreads();
    for (int off = 1; off < 512; off <<= 1) {
        int v = (tid >= off) ? s[tid - off] : 0;
        __syncthreads();
        s[tid] += v;
        __syncthreads();
    }
    if (tid < nblk) bsums[tid] = s[tid] - orig;
}

// row_ptr = blockBase + intra-block exclusive scan; also cursor copy + dinv
__global__ __launch_bounds__(256) void rowptr_kernel(
    const int* __restrict__ cnt, const int* __restrict__ bsums,
    int* __restrict__ row_ptr, int* __restrict__ cursor,
    float* __restrict__ dinv, int N) {
    __shared__ int s[256];
    int tid = threadIdx.x, i = blockIdx.x * 256 + tid;
    int c = (i < N) ? cnt[i] : 0;
    s[tid] = c;
    __syncthreads();
    for (int off = 1; off < 256; off <<= 1) {
        int v = (tid >= off) ? s[tid - off] : 0;
        __syncthreads();
        s[tid] += v;
        __syncthreads();
    }
    if (i < N) {
        int excl = s[tid] - c + bsums[blockIdx.x];
        row_ptr[i] = excl;
        cursor[i]  = excl;
        dinv[i]    = rsqrtf((float)c + 1.0f);  // +1 = self-loop
    }
}

// partitioned fill: 8 replicas per edge-chunk; replica p fills only dst range p.
__global__ __launch_bounds__(256) void fill_part_kernel(
    const int* __restrict__ src, const int* __restrict__ dst,
    int* __restrict__ cursor, int* __restrict__ col, int E, int psz) {
    int part  = blockIdx.x & 7;
    int chunk = blockIdx.x >> 3;
    int i = chunk * 256 + threadIdx.x;
    if (i >= E) return;
    int d = dst[i];
    if (d / psz == part) {
        int p = atomicAdd(&cursor[d], 1);
        col[p] = src[i];
    }
}

// ================= GEMM: g = bf16((X@W) * dinv[row]) =================
// block = 256 = 4 rows x 64 cols; W staged in LDS. Row N = sentinel zeros.

__global__ __launch_bounds__(256) void gemm_scale_kernel(
    const float* __restrict__ X, const float* __restrict__ W,
    const float* __restrict__ dinv, __hip_bfloat16* __restrict__ g, int N) {
    __shared__ float Ws[HID * HID];
    __shared__ float xs[4 * HID];
    int tid = threadIdx.x;
    for (int i = tid; i < HID * HID; i += 256) Ws[i] = W[i];
    int lr = tid >> 6, c = tid & 63;
    int row = blockIdx.x * 4 + lr;
    if (row < N) xs[lr * HID + c] = X[(size_t)row * HID + c];
    __syncthreads();
    if (row >= N) {
        if (row == N) g[(size_t)row * HID + c] = __float2bfloat16(0.f);  // sentinel
        return;
    }
    float acc = 0.f;
#pragma unroll
    for (int k = 0; k < HID; ++k) acc = fmaf(xs[lr * HID + k], Ws[k * HID + c], acc);
    g[(size_t)row * HID + c] = __float2bfloat16(acc * dinv[row]);
}

// ================= gather-reduce + fused finalize =================
// one wave per node. bf16 g: 16 lanes per edge row (ushort4 = 4 feats, 8B/lane),
// quarter = lane>>4 selects one of FOUR edges per wave-load (512B in flight per
// load, 4 loads unrolled = 16 edges/round = a whole typical node). f32 accum.
// OOB edge slots pad to sentinel row N (zeros).
// EPI: 0 = none, 1 = relu, 2 = log_softmax

template <int EPI>
__global__ __launch_bounds__(256) void aggregate_kernel(
    const __hip_bfloat16* __restrict__ g, const int* __restrict__ row_ptr,
    const int* __restrict__ cnt, const int* __restrict__ col,
    const float* __restrict__ dinv, const float* __restrict__ b,
    float* __restrict__ out, int N) {
    int tid = threadIdx.x;
    int n = blockIdx.x * 4 + (tid >> 6);
    if (n >= N) return;
    int lane = tid & 63;
    int quarter = lane >> 4;  // which edge of the 4-group
    int fq      = lane & 15;  // feature-quad index (feats 4fq..4fq+3)

    int beg = __builtin_amdgcn_readfirstlane(row_ptr[n]);
    int deg = __builtin_amdgcn_readfirstlane(cnt[n]);
    float dn = __uint_as_float(__builtin_amdgcn_readfirstlane(__float_as_uint(dinv[n])));

    const ushort4* g4 = (const ushort4*)g;  // row stride = 16 ushort4
    float4 bb = ((const float4*)b)[fq];

    float4 a0 = make_float4(0.f, 0.f, 0.f, 0.f), a1 = a0, a2 = a0, a3 = a0;

#define ACC(A, V)                                   \
    A.x += bf2f(V.x); A.y += bf2f(V.y);             \
    A.z += bf2f(V.z); A.w += bf2f(V.w);

    int base = 0;
    for (; base + 64 <= deg; base += 64) {  // full 64-edge batches (rare)
        int c = col[beg + base + lane];
#pragma unroll
        for (int jj = 0; jj < 16; jj += 4) {
            int s0 = __shfl(c, 4 * (jj + 0) + quarter, 64);
            int s1 = __shfl(c, 4 * (jj + 1) + quarter, 64);
            int s2 = __shfl(c, 4 * (jj + 2) + quarter, 64);
            int s3 = __shfl(c, 4 * (jj + 3) + quarter, 64);
            ushort4 v0 = g4[(size_t)s0 * 16 + fq];
            ushort4 v1 = g4[(size_t)s1 * 16 + fq];
            ushort4 v2 = g4[(size_t)s2 * 16 + fq];
            ushort4 v3 = g4[(size_t)s3 * 16 + fq];
            ACC(a0, v0) ACC(a1, v1) ACC(a2, v2) ACC(a3, v3)
        }
    }
    int rem = deg - base;
    if (rem > 0) {
        int c = (lane < rem) ? col[beg + base + lane] : N;  // pad with sentinel
        int quads = (rem + 3) >> 2;
        int jj = 0;
        for (; jj + 4 <= quads; jj += 4) {
            int s0 = __shfl(c, 4 * (jj + 0) + quarter, 64);
            int s1 = __shfl(c, 4 * (jj + 1) + quarter, 64);
            int s2 = __shfl(c, 4 * (jj + 2) + quarter, 64);
            int s3 = __shfl(c, 4 * (jj + 3) + quarter, 64);
            ushort4 v0 = g4[(size_t)s0 * 16 + fq];
            ushort4 v1 = g4[(size_t)s1 * 16 + fq];
            ushort4 v2 = g4[(size_t)s2 * 16 + fq];
            ushort4 v3 = g4[(size_t)s3 * 16 + fq];
            ACC(a0, v0) ACC(a1, v1) ACC(a2, v2) ACC(a3, v3)
        }
        for (; jj < quads; ++jj) {
            int s0 = __shfl(c, 4 * jj + quarter, 64);
            ushort4 v0 = g4[(size_t)s0 * 16 + fq];
            ACC(a0, v0)
        }
    }
#undef ACC

    float4 t;
    t.x = (a0.x + a1.x) + (a2.x + a3.x);
    t.y = (a0.y + a1.y) + (a2.y + a3.y);
    t.z = (a0.z + a1.z) + (a2.z + a3.z);
    t.w = (a0.w + a1.w) + (a2.w + a3.w);
    // combine the 4 quarter partials (lanes l, l^16, l^32, l^48 share fq)
    t.x += __shfl_xor(t.x, 16, 64); t.x += __shfl_xor(t.x, 32, 64);
    t.y += __shfl_xor(t.y, 16, 64); t.y += __shfl_xor(t.y, 32, 64);
    t.z += __shfl_xor(t.z, 16, 64); t.z += __shfl_xor(t.z, 32, 64);
    t.w += __shfl_xor(t.w, 16, 64); t.w += __shfl_xor(t.w, 32, 64);
    // self-loop term
    ushort4 sv = g4[(size_t)n * 16 + fq];
    t.x += bf2f(sv.x); t.y += bf2f(sv.y); t.z += bf2f(sv.z); t.w += bf2f(sv.w);

    float4 v;
    v.x = dn * t.x + bb.x; v.y = dn * t.y + bb.y;
    v.z = dn * t.z + bb.z; v.w = dn * t.w + bb.w;
    if (EPI == 1) {
        v.x = fmaxf(v.x, 0.f); v.y = fmaxf(v.y, 0.f);
        v.z = fmaxf(v.z, 0.f); v.w = fmaxf(v.w, 0.f);
    }
    if (EPI == 2) {
        float mx = fmaxf(fmaxf(v.x, v.y), fmaxf(v.z, v.w));
#pragma unroll
        for (int o = 8; o > 0; o >>= 1) mx = fmaxf(mx, __shfl_xor(mx, o, 64));
        float sum = expf(v.x - mx) + expf(v.y - mx) + expf(v.z - mx) + expf(v.w - mx);
#pragma unroll
        for (int o = 8; o > 0; o >>= 1) sum += __shfl_xor(sum, o, 64);
        float ls = mx + logf(sum);
        v.x -= ls; v.y -= ls; v.z -= ls; v.w -= ls;
    }
    if (quarter == 0) ((float4*)out)[(size_t)n * 16 + fq] = v;
}

// ================= launcher =================

static inline size_t alignup(size_t x) { return (x + 255) & ~(size_t)255; }

extern "C" void kernel_launch(void* const* d_in, const int* in_sizes, int n_in,
                              void* d_out, int out_size, void* d_ws, size_t ws_size,
                              hipStream_t stream) {
    const float* x  = (const float*)d_in[0];
    const int*   ei = (const int*)d_in[1];
    const float* W1 = (const float*)d_in[2];
    const float* b1 = (const float*)d_in[3];
    const float* W2 = (const float*)d_in[4];
    const float* b2 = (const float*)d_in[5];

    const int N = in_sizes[0] / HID;  // 100000
    const int E = in_sizes[1] / 2;    // 1600000
    const int* src = ei;
    const int* dst = ei + E;

    const int nblk = (N + 255) / 256;  // 391 (<=512 required by scan)
    const int psz  = (N + 7) / 8;      // dst-range partition size

    char* w = (char*)d_ws;
    float*          dinv    = (float*)w; w += alignup((size_t)N * 4);
    __hip_bfloat16* g       = (__hip_bfloat16*)w; w += alignup((size_t)(N + 1) * HID * 2);
    int*            cnt     = (int*)w;   w += alignup((size_t)N * 4);
    int*            row_ptr = (int*)w;   w += alignup((size_t)N * 4);
    int*            cursor  = (int*)w;   w += alignup((size_t)N * 4);
    int*            col     = (int*)w;   w += alignup((size_t)E * 4);
    int*            bsums   = (int*)w;   w += alignup((size_t)nblk * 4);

    float* xbuf = (float*)d_out;  // intermediate activations live in d_out

    const int egrid = (E + 255) / 256;
    const int ngrid = (N + 3) / 4;       // aggregate grid
    const int ggrid = (N + 1 + 3) / 4;   // gemm grid covers sentinel row N

    // ---- CSR build (once; reused by all 3 convs) ----
    hipMemsetAsync(cnt, 0, (size_t)N * sizeof(int), stream);
    hist_kernel<<<egrid, 256, 0, stream>>>(dst, cnt, E);
    bsum_kernel<<<nblk, 256, 0, stream>>>(cnt, bsums, N);
    scan_bsums_kernel<<<1, 512, 0, stream>>>(bsums, nblk);
    rowptr_kernel<<<nblk, 256, 0, stream>>>(cnt, bsums, row_ptr, cursor, dinv, N);
    fill_part_kernel<<<egrid * 8, 256, 0, stream>>>(src, dst, cursor, col, E, psz);

    // ---- conv1: W1,b1 ----
    gemm_scale_kernel<<<ggrid, 256, 0, stream>>>(x, W1, dinv, g, N);
    aggregate_kernel<0><<<ngrid, 256, 0, stream>>>(g, row_ptr, cnt, col, dinv, b1, xbuf, N);

    // ---- conv2: W1,b1 + relu ----
    gemm_scale_kernel<<<ggrid, 256, 0, stream>>>(xbuf, W1, dinv, g, N);
    aggregate_kernel<1><<<ngrid, 256, 0, stream>>>(g, row_ptr, cnt, col, dinv, b1, xbuf, N);

    // ---- conv3: W2,b2 + log_softmax ----
    gemm_scale_kernel<<<ggrid, 256, 0, stream>>>(xbuf, W2, dinv, g, N);
    aggregate_kernel<2><<<ngrid, 256, 0, stream>>>(g, row_ptr, cnt, col, dinv, b2, (float*)d_out, N);
}

// Round 9
// 405.821 us; speedup vs baseline: 10.7155x; 1.1418x over previous
//
#include <hip/hip_runtime.h>
#include <hip/hip_bf16.h>

#define HID 64

// ---- bf16 helpers: a[0..7] += bf16x8 packed in uint4 (feat even = low half) ----
__device__ __forceinline__ void acc8(float* a, uint4 v) {
    a[0] += __uint_as_float(v.x << 16);
    a[1] += __uint_as_float(v.x & 0xffff0000u);
    a[2] += __uint_as_float(v.y << 16);
    a[3] += __uint_as_float(v.y & 0xffff0000u);
    a[4] += __uint_as_float(v.z << 16);
    a[5] += __uint_as_float(v.z & 0xffff0000u);
    a[6] += __uint_as_float(v.w << 16);
    a[7] += __uint_as_float(v.w & 0xffff0000u);
}

// ================= CSR build (by dst) =================

// partitioned hist: replica p counts only dst range p -> cnt atomics stay L2-local
__global__ __launch_bounds__(256) void hist_part_kernel(
    const int* __restrict__ dst, int* __restrict__ cnt, int E, int psz) {
    int part = blockIdx.x & 7, chunk = blockIdx.x >> 3;
    int i = chunk * 256 + threadIdx.x;
    if (i >= E) return;
    int d = dst[i];
    if (d / psz == part) atomicAdd(&cnt[d], 1);
}

__global__ __launch_bounds__(256) void bsum_kernel(const int* __restrict__ cnt,
                                                   int* __restrict__ bsums, int N) {
    __shared__ int s[256];
    int tid = threadIdx.x, i = blockIdx.x * 256 + tid;
    s[tid] = (i < N) ? cnt[i] : 0;
    __syncthreads();
    for (int o = 128; o > 0; o >>= 1) {
        if (tid < o) s[tid] += s[tid + o];
        __syncthreads();
    }
    if (tid == 0) bsums[blockIdx.x] = s[0];
}

__global__ __launch_bounds__(512) void scan_bsums_kernel(int* __restrict__ bsums, int nblk) {
    __shared__ int s[512];
    int tid = threadIdx.x;
    int orig = (tid < nblk) ? bsums[tid] : 0;
    s[tid] = orig;
    __syncthreads();
    for (int off = 1; off < 512; off <<= 1) {
        int v = (tid >= off) ? s[tid - off] : 0;
        __syncthreads();
        s[tid] += v;
        __syncthreads();
    }
    if (tid < nblk) bsums[tid] = s[tid] - orig;
}

__global__ __launch_bounds__(256) void rowptr_kernel(
    const int* __restrict__ cnt, const int* __restrict__ bsums,
    int* __restrict__ row_ptr, int* __restrict__ cursor,
    float* __restrict__ dinv, int N) {
    __shared__ int s[256];
    int tid = threadIdx.x, i = blockIdx.x * 256 + tid;
    int c = (i < N) ? cnt[i] : 0;
    s[tid] = c;
    __syncthreads();
    for (int off = 1; off < 256; off <<= 1) {
        int v = (tid >= off) ? s[tid - off] : 0;
        __syncthreads();
        s[tid] += v;
        __syncthreads();
    }
    if (i < N) {
        int excl = s[tid] - c + bsums[blockIdx.x];
        row_ptr[i] = excl;
        cursor[i]  = excl;
        dinv[i]    = rsqrtf((float)c + 1.0f);  // +1 = self-loop
    }
}

// partitioned fill: replica p fills only dst range p (col/cursor writes L2-local)
__global__ __launch_bounds__(256) void fill_part_kernel(
    const int* __restrict__ src, const int* __restrict__ dst,
    int* __restrict__ cursor, int* __restrict__ col, int E, int psz) {
    int part = blockIdx.x & 7, chunk = blockIdx.x >> 3;
    int i = chunk * 256 + threadIdx.x;
    if (i >= E) return;
    int d = dst[i];
    if (d / psz == part) {
        int p = atomicAdd(&cursor[d], 1);
        col[p] = src[i];
    }
}

// ================= shared gather core =================
// one wave per node. bf16 g rows (128B): 8 lanes x uint4 (8 feats) per row,
// eighth = lane>>3 selects one of 8 edges per wave-load (1KB in flight/load).
// f32 accumulate; OOB edge slots pad to sentinel row N (zeros).
// Result: every lane holds t[8] = full aggregate (incl. self) for feats 8fo..8fo+7.
__device__ __forceinline__ void gather64(
    const uint4* __restrict__ g4, const int* __restrict__ col,
    int beg, int deg, int n, int N, int lane, float* t) {
    int eighth = lane >> 3, fo = lane & 7;
    float a0[8] = {}, a1[8] = {}, a2[8] = {}, a3[8] = {};
    for (int base = 0; base < deg; base += 64) {
        int rem = deg - base; rem = rem > 64 ? 64 : rem;
        int c = (lane < rem) ? col[beg + base + lane] : N;  // pad -> sentinel
        int groups = (rem + 7) >> 3;
        int j = 0;
        for (; j + 4 <= groups; j += 4) {
            int s0 = __shfl(c, 8 * (j + 0) + eighth, 64);
            int s1 = __shfl(c, 8 * (j + 1) + eighth, 64);
            int s2 = __shfl(c, 8 * (j + 2) + eighth, 64);
            int s3 = __shfl(c, 8 * (j + 3) + eighth, 64);
            uint4 v0 = g4[(size_t)s0 * 8 + fo];
            uint4 v1 = g4[(size_t)s1 * 8 + fo];
            uint4 v2 = g4[(size_t)s2 * 8 + fo];
            uint4 v3 = g4[(size_t)s3 * 8 + fo];
            acc8(a0, v0); acc8(a1, v1); acc8(a2, v2); acc8(a3, v3);
        }
        if (j + 2 <= groups) {
            int s0 = __shfl(c, 8 * (j + 0) + eighth, 64);
            int s1 = __shfl(c, 8 * (j + 1) + eighth, 64);
            uint4 v0 = g4[(size_t)s0 * 8 + fo];
            uint4 v1 = g4[(size_t)s1 * 8 + fo];
            acc8(a0, v0); acc8(a1, v1);
            j += 2;
        }
        if (j < groups) {
            int s0 = __shfl(c, 8 * j + eighth, 64);
            uint4 v0 = g4[(size_t)s0 * 8 + fo];
            acc8(a0, v0);
        }
    }
    float sf[8] = {};
    acc8(sf, g4[(size_t)n * 8 + fo]);  // self-loop row (added once, after reduce)
#pragma unroll
    for (int k = 0; k < 8; ++k) {
        float s = (a0[k] + a1[k]) + (a2[k] + a3[k]);
        s += __shfl_xor(s, 8, 64);
        s += __shfl_xor(s, 16, 64);
        s += __shfl_xor(s, 32, 64);
        t[k] = s + sf[k];
    }
}

// ================= conv1 GEMM: g = bf16((X@W)*dinv) =================
// grid-stride (2048 blocks): W staged in LDS ONCE per block. Row N = sentinel 0.

__global__ __launch_bounds__(256) void gemm_scale_kernel(
    const float* __restrict__ X, const float* __restrict__ W,
    const float* __restrict__ dinv, __hip_bfloat16* __restrict__ g, int N) {
    __shared__ float Ws[HID * HID];
    __shared__ float4 xs4[4][HID / 4];
    int tid = threadIdx.x;
    for (int i = tid; i < HID * HID; i += 256) Ws[i] = W[i];
    __syncthreads();
    int w = tid >> 6, c = tid & 63;
    float* xsw = (float*)xs4[w];
    int ngrp = (N + 4) / 4;  // covers sentinel row N
    for (int grp = blockIdx.x; grp < ngrp; grp += gridDim.x) {
        int row = grp * 4 + w;
        if (row > N) continue;
        if (row == N) { g[(size_t)N * HID + c] = __float2bfloat16(0.f); continue; }
        xsw[c] = X[(size_t)row * HID + c];  // wave-local LDS slice (in-order DS)
        float acc = 0.f;
#pragma unroll
        for (int k = 0; k < HID; ++k) acc = fmaf(xsw[k], Ws[k * HID + c], acc);
        g[(size_t)row * HID + c] = __float2bfloat16(acc * dinv[row]);
    }
}

// ================= fused aggregate + epilogue + next-conv GEMM =================
// out_row = dinv*t + bias (+relu); g_out = bf16((out_row @ W) * dinv).
// Removes the xbuf f32 round-trip and the separate gemm dispatch.

template <bool RELU>
__global__ __launch_bounds__(256) void agg_gemm_kernel(
    const __hip_bfloat16* __restrict__ g_in, const int* __restrict__ row_ptr,
    const int* __restrict__ cnt, const int* __restrict__ col,
    const float* __restrict__ dinv, const float* __restrict__ bias,
    const float* __restrict__ W, __hip_bfloat16* __restrict__ g_out, int N) {
    __shared__ float Ws[HID * HID];
    __shared__ float4 xs4[4][HID / 4];
    int tid = threadIdx.x;
    for (int i = tid; i < HID * HID; i += 256) Ws[i] = W[i];
    __syncthreads();
    int w = tid >> 6, lane = tid & 63;
    int eighth = lane >> 3, fo = lane & 7;
    const uint4* g4 = (const uint4*)g_in;
    float* xsw = (float*)xs4[w];
    float bb[8];
#pragma unroll
    for (int k = 0; k < 8; ++k) bb[k] = bias[8 * fo + k];  // hoisted
    int ngrp = (N + 4) / 4;
    for (int grp = blockIdx.x; grp < ngrp; grp += gridDim.x) {
        int n = grp * 4 + w;
        if (n > N) continue;
        if (n == N) { g_out[(size_t)N * HID + lane] = __float2bfloat16(0.f); continue; }
        int beg = __builtin_amdgcn_readfirstlane(row_ptr[n]);
        int deg = __builtin_amdgcn_readfirstlane(cnt[n]);
        float dn = __uint_as_float(__builtin_amdgcn_readfirstlane(__float_as_uint(dinv[n])));
        float t[8];
        gather64(g4, col, beg, deg, n, N, lane, t);
        if (eighth == 0) {  // 8 lanes hold distinct fo -> write full row to LDS
            float4 o0, o1;
            o0.x = fmaf(dn, t[0], bb[0]); o0.y = fmaf(dn, t[1], bb[1]);
            o0.z = fmaf(dn, t[2], bb[2]); o0.w = fmaf(dn, t[3], bb[3]);
            o1.x = fmaf(dn, t[4], bb[4]); o1.y = fmaf(dn, t[5], bb[5]);
            o1.z = fmaf(dn, t[6], bb[6]); o1.w = fmaf(dn, t[7], bb[7]);
            if (RELU) {
                o0.x = fmaxf(o0.x, 0.f); o0.y = fmaxf(o0.y, 0.f);
                o0.z = fmaxf(o0.z, 0.f); o0.w = fmaxf(o0.w, 0.f);
                o1.x = fmaxf(o1.x, 0.f); o1.y = fmaxf(o1.y, 0.f);
                o1.z = fmaxf(o1.z, 0.f); o1.w = fmaxf(o1.w, 0.f);
            }
            xs4[w][2 * fo]     = o0;
            xs4[w][2 * fo + 1] = o1;
        }
        // GEMM: lane = output col; wave-local LDS slice, in-order DS pipe
        float acc = 0.f;
#pragma unroll
        for (int k = 0; k < HID; ++k) acc = fmaf(xsw[k], Ws[k * HID + lane], acc);
        g_out[(size_t)n * HID + lane] = __float2bfloat16(acc * dn);
    }
}

// ================= final aggregate + bias + log_softmax -> f32 out =================

__global__ __launch_bounds__(256) void agg_lsm_kernel(
    const __hip_bfloat16* __restrict__ g_in, const int* __restrict__ row_ptr,
    const int* __restrict__ cnt, const int* __restrict__ col,
    const float* __restrict__ dinv, const float* __restrict__ bias,
    float* __restrict__ out, int N) {
    int tid = threadIdx.x;
    int n = blockIdx.x * 4 + (tid >> 6);
    if (n >= N) return;
    int lane = tid & 63;
    int eighth = lane >> 3, fo = lane & 7;
    int beg = __builtin_amdgcn_readfirstlane(row_ptr[n]);
    int deg = __builtin_amdgcn_readfirstlane(cnt[n]);
    float dn = __uint_as_float(__builtin_amdgcn_readfirstlane(__float_as_uint(dinv[n])));
    const uint4* g4 = (const uint4*)g_in;
    float t[8];
    gather64(g4, col, beg, deg, n, N, lane, t);
    float v[8];
#pragma unroll
    for (int k = 0; k < 8; ++k) v[k] = fmaf(dn, t[k], bias[8 * fo + k]);
    float mx = v[0];
#pragma unroll
    for (int k = 1; k < 8; ++k) mx = fmaxf(mx, v[k]);
    mx = fmaxf(mx, __shfl_xor(mx, 1, 64));
    mx = fmaxf(mx, __shfl_xor(mx, 2, 64));
    mx = fmaxf(mx, __shfl_xor(mx, 4, 64));
    float sum = 0.f;
#pragma unroll
    for (int k = 0; k < 8; ++k) sum += expf(v[k] - mx);
    sum += __shfl_xor(sum, 1, 64);
    sum += __shfl_xor(sum, 2, 64);
    sum += __shfl_xor(sum, 4, 64);
    float ls = mx + logf(sum);
    if (eighth == 0) {
        float4 o0 = make_float4(v[0] - ls, v[1] - ls, v[2] - ls, v[3] - ls);
        float4 o1 = make_float4(v[4] - ls, v[5] - ls, v[6] - ls, v[7] - ls);
        ((float4*)out)[(size_t)n * 16 + 2 * fo]     = o0;
        ((float4*)out)[(size_t)n * 16 + 2 * fo + 1] = o1;
    }
}

// ================= launcher =================

static inline size_t alignup(size_t x) { return (x + 255) & ~(size_t)255; }

extern "C" void kernel_launch(void* const* d_in, const int* in_sizes, int n_in,
                              void* d_out, int out_size, void* d_ws, size_t ws_size,
                              hipStream_t stream) {
    const float* x  = (const float*)d_in[0];
    const int*   ei = (const int*)d_in[1];
    const float* W1 = (const float*)d_in[2];
    const float* b1 = (const float*)d_in[3];
    const float* W2 = (const float*)d_in[4];
    const float* b2 = (const float*)d_in[5];

    const int N = in_sizes[0] / HID;  // 100000
    const int E = in_sizes[1] / 2;    // 1600000
    const int* src = ei;
    const int* dst = ei + E;

    const int nblk = (N + 255) / 256;  // 391 (<=512 required by scan)
    const int psz  = (N + 7) / 8;      // dst-range partition size

    char* w = (char*)d_ws;
    float*          dinv    = (float*)w;          w += alignup((size_t)N * 4);
    __hip_bfloat16* gA      = (__hip_bfloat16*)w; w += alignup((size_t)(N + 1) * HID * 2);
    __hip_bfloat16* gB      = (__hip_bfloat16*)w; w += alignup((size_t)(N + 1) * HID * 2);
    int*            cnt     = (int*)w;            w += alignup((size_t)N * 4);
    int*            row_ptr = (int*)w;            w += alignup((size_t)N * 4);
    int*            cursor  = (int*)w;            w += alignup((size_t)N * 4);
    int*            col     = (int*)w;            w += alignup((size_t)E * 4);
    int*            bsums   = (int*)w;            w += alignup((size_t)nblk * 4);

    const int egrid = (E + 255) / 256;
    const int ngrid = (N + 3) / 4;   // final aggregate grid
    const int gsgrid = 2048;         // grid-stride kernels (W amortized per block)

    // ---- CSR build (once; reused by all 3 convs) ----
    hipMemsetAsync(cnt, 0, (size_t)N * sizeof(int), stream);
    hist_part_kernel<<<egrid * 8, 256, 0, stream>>>(dst, cnt, E, psz);
    bsum_kernel<<<nblk, 256, 0, stream>>>(cnt, bsums, N);
    scan_bsums_kernel<<<1, 512, 0, stream>>>(bsums, nblk);
    rowptr_kernel<<<nblk, 256, 0, stream>>>(cnt, bsums, row_ptr, cursor, dinv, N);
    fill_part_kernel<<<egrid * 8, 256, 0, stream>>>(src, dst, cursor, col, E, psz);

    // ---- conv1 GEMM: gA = (x@W1)*dinv ----
    gemm_scale_kernel<<<gsgrid, 256, 0, stream>>>(x, W1, dinv, gA, N);
    // ---- conv1 agg + b1 | conv2 GEMM: gB = ((agg(gA)+b1)@W1)*dinv ----
    agg_gemm_kernel<false><<<gsgrid, 256, 0, stream>>>(gA, row_ptr, cnt, col, dinv, b1, W1, gB, N);
    // ---- conv2 agg + b1 + relu | conv3 GEMM: gA = (relu(agg(gB)+b1)@W2)*dinv ----
    agg_gemm_kernel<true><<<gsgrid, 256, 0, stream>>>(gB, row_ptr, cnt, col, dinv, b1, W2, gA, N);
    // ---- conv3 agg + b2 + log_softmax -> d_out ----
    agg_lsm_kernel<<<ngrid, 256, 0, stream>>>(gA, row_ptr, cnt, col, dinv, b2, (float*)d_out, N);
}